// Round 4
// baseline (675.140 us; speedup 1.0000x reference)
//
#include <hip/hip_runtime.h>
#include <hip/hip_bf16.h>
#include <math.h>

// Problem constants: N=64, L=1024, H=1024
#define N_  64
#define L_  1024
#define H_  1024
#define NL_ (N_ * L_)

typedef __attribute__((ext_vector_type(8))) short bf16x8;   // 8 bf16 = 4 VGPRs
typedef __attribute__((ext_vector_type(4))) float f32x4;
typedef unsigned short ushort_t;
typedef unsigned int uint_t;

// ---------------------------------------------------------------------------
// K0: fp32 -> bf16 (RNE) for Ws only (2 MB out), grid-strided
// ---------------------------------------------------------------------------
__device__ inline ushort_t f32_to_bf16_rne(float f) {
    uint_t u = __float_as_uint(f);
    u += 0x7FFFu + ((u >> 16) & 1u);
    return (ushort_t)(u >> 16);
}

__global__ __launch_bounds__(256) void convert_bf16_kernel(const float* __restrict__ src,
                                                           ushort_t* __restrict__ dst,
                                                           size_t nvec8) {
    size_t stride = (size_t)gridDim.x * 256;
    for (size_t g = (size_t)blockIdx.x * 256 + threadIdx.x; g < nvec8; g += stride) {
        size_t i = g * 8;
        float4 a = *(const float4*)(src + i);
        float4 b = *(const float4*)(src + i + 4);
        union { bf16x8 v; ushort_t u[8]; } o;
        o.u[0] = f32_to_bf16_rne(a.x); o.u[1] = f32_to_bf16_rne(a.y);
        o.u[2] = f32_to_bf16_rne(a.z); o.u[3] = f32_to_bf16_rne(a.w);
        o.u[4] = f32_to_bf16_rne(b.x); o.u[5] = f32_to_bf16_rne(b.y);
        o.u[6] = f32_to_bf16_rne(b.z); o.u[7] = f32_to_bf16_rne(b.w);
        *(bf16x8*)(dst + i) = o.v;
    }
}

// ---------------------------------------------------------------------------
// K1: dh[n][k] = sum_h ddec[n][h] * Wh[k][h]   (fp32, tiny: 0.13 GFLOP)
// ---------------------------------------------------------------------------
__global__ __launch_bounds__(256) void dh_kernel(const float* __restrict__ ddec,
                                                 const float* __restrict__ Wh,
                                                 float* __restrict__ dh) {
    int i = blockIdx.x * 256 + threadIdx.x;
    int n = i >> 10;
    const float* a = ddec + (size_t)n * H_;
    const float* w = Wh + (size_t)(i & (H_ - 1)) * H_;
    float acc = 0.f;
#pragma unroll 8
    for (int h = 0; h < H_; h += 4) {
        float4 av = *(const float4*)(a + h);
        float4 wv = *(const float4*)(w + h);
        acc += av.x * wv.x + av.y * wv.y + av.z * wv.z + av.w * wv.w;
    }
    dh[i] = acc;
}

// ---------------------------------------------------------------------------
// K2: MFMA score GEMM. A = enc fp32 (converted to bf16 during staging via
// v_perm truncation), B = Ws pre-converted bf16 via global_load_lds.
//   C[i][k] = sum_h enc[i][h] * Ws[k][h]
//   score[i] += sum_k v[k] * tanh(dh[n][k] + C[i][k])
// Tile 128(i) x 128(k), BK=32, 4 waves x (4x4 frags of 16x16x32_bf16).
// LDS chunk swizzle: row r chunk q stored at slot r*4 + (q ^ ((r>>1)&3)).
// Grid 4096 1-D: k_tile=(b>>3)&7, i_tile=(b&7)|((b>>6)<<3) so the 8 k-tiles
// of an i-tile share an XCD (b%8 round-robin) -> enc fetched from HBM once.
// ---------------------------------------------------------------------------
__device__ inline uint_t pack_bf16_trunc(float lo, float hi) {
    // result = (bits(lo)>>16) | (bits(hi) & 0xFFFF0000)  == v_perm_b32
    return __builtin_amdgcn_perm(__float_as_uint(hi), __float_as_uint(lo), 0x07060302u);
}

__device__ inline void stage_tile_bf16(const ushort_t* __restrict__ gbase,
                                       ushort_t* lds, int tid, size_t row0_off) {
#pragma unroll
    for (int j = 0; j < 2; j++) {
        int c_lin = j * 256 + tid;
        int r  = c_lin >> 2;
        int cp = c_lin & 3;
        int q  = cp ^ ((r >> 1) & 3);
        const ushort_t* g = gbase + row0_off + (size_t)r * H_ + q * 8;
        ushort_t* l = lds + (size_t)(j * 256 + (tid & ~63)) * 8;  // wave-uniform
        __builtin_amdgcn_global_load_lds((const __attribute__((address_space(1))) void*)g,
                                         (__attribute__((address_space(3))) void*)l,
                                         16, 0, 0);
    }
}

__global__ __launch_bounds__(256) void score_mfma_kernel(const float* __restrict__ enc,
                                                         const ushort_t* __restrict__ ws_bf,
                                                         const float* __restrict__ dh,
                                                         const float* __restrict__ v,
                                                         float* __restrict__ score) {
    __shared__ ushort_t As[128 * 32];   // 8 KB (bf16, converted in staging)
    __shared__ ushort_t Bs[128 * 32];   // 8 KB

    const int b  = blockIdx.x;
    const int i0 = ((b & 7) | ((b >> 6) << 3)) * 128;   // i-tile base
    const int k0 = ((b >> 3) & 7) * 128;                // k-tile base
    const int tid  = threadIdx.x;
    const int lane = tid & 63;
    const int wv   = tid >> 6;
    const int wr   = (wv >> 1) * 64;    // wave row base in tile
    const int wc   = (wv & 1) * 64;     // wave col base in tile
    const int m    = lane & 15;
    const int q    = lane >> 4;
    const int qs   = q ^ ((m >> 1) & 3);  // swizzled chunk col for reads

    f32x4 acc[4][4];
#pragma unroll
    for (int a = 0; a < 4; a++)
#pragma unroll
        for (int c = 0; c < 4; c++)
            acc[a][c] = (f32x4){0.f, 0.f, 0.f, 0.f};

    for (int h0 = 0; h0 < H_; h0 += 32) {
        __syncthreads();
        // B tile: bf16 async DMA
        stage_tile_bf16(ws_bf, Bs, tid, (size_t)k0 * H_ + h0);
        // A tile: fp32 -> bf16 (truncate) through VGPRs, same swizzled layout
#pragma unroll
        for (int j = 0; j < 2; j++) {
            int c_lin = j * 256 + tid;
            int r  = c_lin >> 2;
            int cp = c_lin & 3;
            int qg = cp ^ ((r >> 1) & 3);
            const float* g = enc + (size_t)(i0 + r) * H_ + h0 + qg * 8;
            float4 fa = *(const float4*)g;
            float4 fb = *(const float4*)(g + 4);
            uint4 o;
            o.x = pack_bf16_trunc(fa.x, fa.y);
            o.y = pack_bf16_trunc(fa.z, fa.w);
            o.z = pack_bf16_trunc(fb.x, fb.y);
            o.w = pack_bf16_trunc(fb.z, fb.w);
            *(uint4*)(As + (size_t)c_lin * 8) = o;
        }
        __syncthreads();

        bf16x8 af[4], bfr[4];
#pragma unroll
        for (int ti = 0; ti < 4; ti++) {
            int r = wr + ti * 16 + m;
            af[ti] = *(const bf16x8*)(As + (size_t)(r * 4 + qs) * 8);
        }
#pragma unroll
        for (int tj = 0; tj < 4; tj++) {
            int r = wc + tj * 16 + m;
            bfr[tj] = *(const bf16x8*)(Bs + (size_t)(r * 4 + qs) * 8);
        }
#pragma unroll
        for (int ti = 0; ti < 4; ti++)
#pragma unroll
            for (int tj = 0; tj < 4; tj++)
                acc[ti][tj] = __builtin_amdgcn_mfma_f32_16x16x32_bf16(
                    af[ti], bfr[tj], acc[ti][tj], 0, 0, 0);
    }

    // Epilogue: x = dh + C; s_row += v[k] * tanh(x); wave-reduce over 64 k,
    // one atomicAdd per row per wave.
    const int nb = i0 >> 10;            // batch index (tile never crosses n)
    float vv[4], dhv[4];
#pragma unroll
    for (int tj = 0; tj < 4; tj++) {
        int k = k0 + wc + tj * 16 + m;  // C/D col = lane&15
        vv[tj]  = v[k];
        dhv[tj] = dh[nb * H_ + k];
    }
#pragma unroll
    for (int ti = 0; ti < 4; ti++) {
#pragma unroll
        for (int reg = 0; reg < 4; reg++) {
            float s = 0.f;
#pragma unroll
            for (int tj = 0; tj < 4; tj++) {
                float x  = dhv[tj] + acc[ti][tj][reg];
                float e2 = __expf(2.f * x);
                s += vv[tj] * (1.f - 2.f / (e2 + 1.f));   // tanh, saturates +/-1
            }
            s += __shfl_xor(s, 1);
            s += __shfl_xor(s, 2);
            s += __shfl_xor(s, 4);
            s += __shfl_xor(s, 8);
            if (m == 0) {
                int i_local = wr + ti * 16 + q * 4 + reg;   // C/D row = quad*4+reg
                atomicAdd(&score[i0 + i_local], s);
            }
        }
    }
}

// ---------------------------------------------------------------------------
// K3: masked softmax over L per batch row; writes attn to d_out[65536..]
// ---------------------------------------------------------------------------
__global__ __launch_bounds__(256) void softmax_kernel(const float* __restrict__ score,
                                                      const int* __restrict__ mask,
                                                      float* __restrict__ attn) {
    const int n = blockIdx.x;
    const int t = threadIdx.x;
    __shared__ float redmax[4];
    __shared__ float redsum[4];

    float s[4];
    int   mk[4];
    float mymax = -INFINITY;
#pragma unroll
    for (int j = 0; j < 4; j++) {
        int l = t + j * 256;
        mk[j] = mask[n * L_ + l];
        s[j] = mk[j] ? -INFINITY : score[n * L_ + l];
        mymax = fmaxf(mymax, s[j]);
    }
#pragma unroll
    for (int off = 1; off < 64; off <<= 1)
        mymax = fmaxf(mymax, __shfl_xor(mymax, off));
    if ((t & 63) == 0) redmax[t >> 6] = mymax;
    __syncthreads();
    float gmax = fmaxf(fmaxf(redmax[0], redmax[1]), fmaxf(redmax[2], redmax[3]));

    float e[4];
    float mysum = 0.f;
#pragma unroll
    for (int j = 0; j < 4; j++) {
        e[j] = mk[j] ? 0.f : __expf(s[j] - gmax);
        mysum += e[j];
    }
#pragma unroll
    for (int off = 1; off < 64; off <<= 1)
        mysum += __shfl_xor(mysum, off);
    if ((t & 63) == 0) redsum[t >> 6] = mysum;
    __syncthreads();
    float gsum = redsum[0] + redsum[1] + redsum[2] + redsum[3];
    float inv = 1.f / gsum;
#pragma unroll
    for (int j = 0; j < 4; j++)
        attn[n * L_ + t + j * 256] = e[j] * inv;
}

// ---------------------------------------------------------------------------
// K4: context[n][h] = sum_l attn[n][l] * enc[n][l][h]  (fp32)
// grid (64, 8): block (n, L-chunk of 128); 256 thr x 4 h (float4, 16B/lane).
// fp32 atomicAdd partials into zero-initialized ctx (8 blocks per address).
// ---------------------------------------------------------------------------
__global__ __launch_bounds__(256) void context_kernel(const float* __restrict__ enc,
                                                      const float* __restrict__ attn,
                                                      float* __restrict__ ctx) {
    const int n  = blockIdx.x;
    const int l0 = blockIdx.y * 128;
    const int t  = threadIdx.x;      // 0..255
    const int h0 = t * 4;

    __shared__ float w[128];
    if (t < 128) w[t] = attn[n * L_ + l0 + t];
    __syncthreads();

    const float* base = enc + ((size_t)n * L_ + l0) * H_ + h0;
    float ax = 0.f, ay = 0.f, az = 0.f, aw = 0.f;
#pragma unroll 8
    for (int l = 0; l < 128; l++) {
        float4 e = *(const float4*)(base + (size_t)l * H_);
        float wl = w[l];
        ax += wl * e.x; ay += wl * e.y; az += wl * e.z; aw += wl * e.w;
    }
    atomicAdd(&ctx[n * H_ + h0 + 0], ax);
    atomicAdd(&ctx[n * H_ + h0 + 1], ay);
    atomicAdd(&ctx[n * H_ + h0 + 2], az);
    atomicAdd(&ctx[n * H_ + h0 + 3], aw);
}

// ---------------------------------------------------------------------------
extern "C" void kernel_launch(void* const* d_in, const int* in_sizes, int n_in,
                              void* d_out, int out_size, void* d_ws, size_t ws_size,
                              hipStream_t stream) {
    const float* ddec = (const float*)d_in[0];   // [64,1024] f32
    const float* enc  = (const float*)d_in[1];   // [64,1024,1024] f32
    const int*   mask = (const int*)d_in[2];     // [64,1024]
    const float* Wh   = (const float*)d_in[3];   // [1024,1024] f32
    const float* Ws   = (const float*)d_in[4];   // [1024,1024] f32
    const float* v    = (const float*)d_in[5];   // [1024] f32

    float* out_ctx  = (float*)d_out;             // [64,1024]
    float* out_attn = out_ctx + N_ * H_;         // [64,1024]

    // ws layout (total ~2.5 MB): ws_bf (2 MB) | dh (256 KB) | score (256 KB)
    ushort_t* ws_bf = (ushort_t*)d_ws;
    float*    dh    = (float*)(ws_bf + (size_t)H_ * H_);
    float*    score = dh + N_ * H_;

    convert_bf16_kernel<<<512, 256, 0, stream>>>(Ws, ws_bf, (size_t)H_ * H_ / 8);

    hipMemsetAsync(score, 0, (size_t)NL_ * sizeof(float), stream);
    hipMemsetAsync(out_ctx, 0, (size_t)N_ * H_ * sizeof(float), stream);

    dh_kernel<<<NL_ / 256, 256, 0, stream>>>(ddec, Wh, dh);

    score_mfma_kernel<<<4096, 256, 0, stream>>>(enc, ws_bf, dh, v, score);

    softmax_kernel<<<N_, 256, 0, stream>>>(score, mask, out_attn);

    dim3 g4(N_, 8);
    context_kernel<<<g4, 256, 0, stream>>>(enc, out_attn, out_ctx);
}

// Round 5
// 643.743 us; speedup vs baseline: 1.0488x; 1.0488x over previous
//
#include <hip/hip_runtime.h>
#include <hip/hip_bf16.h>
#include <math.h>

// Problem constants: N=64, L=1024, H=1024
#define N_  64
#define L_  1024
#define H_  1024
#define NL_ (N_ * L_)

typedef __attribute__((ext_vector_type(8))) short bf16x8;   // 8 bf16 = 4 VGPRs
typedef __attribute__((ext_vector_type(4))) float f32x4;
typedef unsigned short ushort_t;
typedef unsigned int uint_t;

// ---------------------------------------------------------------------------
// K0: fp32 -> bf16 (RNE), grid-strided, 8 elements/thread/iter, 16B stores
// ---------------------------------------------------------------------------
__device__ inline ushort_t f32_to_bf16_rne(float f) {
    uint_t u = __float_as_uint(f);
    u += 0x7FFFu + ((u >> 16) & 1u);
    return (ushort_t)(u >> 16);
}

__global__ __launch_bounds__(256) void convert_bf16_kernel(const float* __restrict__ src,
                                                           ushort_t* __restrict__ dst,
                                                           size_t nvec8) {
    size_t stride = (size_t)gridDim.x * 256;
    for (size_t g = (size_t)blockIdx.x * 256 + threadIdx.x; g < nvec8; g += stride) {
        size_t i = g * 8;
        float4 a = *(const float4*)(src + i);
        float4 b = *(const float4*)(src + i + 4);
        union { bf16x8 v; ushort_t u[8]; } o;
        o.u[0] = f32_to_bf16_rne(a.x); o.u[1] = f32_to_bf16_rne(a.y);
        o.u[2] = f32_to_bf16_rne(a.z); o.u[3] = f32_to_bf16_rne(a.w);
        o.u[4] = f32_to_bf16_rne(b.x); o.u[5] = f32_to_bf16_rne(b.y);
        o.u[6] = f32_to_bf16_rne(b.z); o.u[7] = f32_to_bf16_rne(b.w);
        *(bf16x8*)(dst + i) = o.v;
    }
}

// ---------------------------------------------------------------------------
// K1: dh[n][k] = sum_h ddec[n][h] * Wh[k][h]   (fp32, tiny: 0.13 GFLOP)
// ---------------------------------------------------------------------------
__global__ __launch_bounds__(256) void dh_kernel(const float* __restrict__ ddec,
                                                 const float* __restrict__ Wh,
                                                 float* __restrict__ dh) {
    int i = blockIdx.x * 256 + threadIdx.x;
    int n = i >> 10;
    const float* a = ddec + (size_t)n * H_;
    const float* w = Wh + (size_t)(i & (H_ - 1)) * H_;
    float acc = 0.f;
#pragma unroll 8
    for (int h = 0; h < H_; h += 4) {
        float4 av = *(const float4*)(a + h);
        float4 wv = *(const float4*)(w + h);
        acc += av.x * wv.x + av.y * wv.y + av.z * wv.z + av.w * wv.w;
    }
    dh[i] = acc;
}

// ---------------------------------------------------------------------------
// K2: MFMA score GEMM (R3 known-good: 212 us, MfmaUtil 28%).
//   C[i][k] = sum_h enc_bf[i][h] * ws_bf[k][h]
//   score[i] += sum_k v[k] * tanh(dh[n][k] + C[i][k])
// Tile 128x128, BK=32, 4 waves x (4x4 frags of 16x16x32_bf16), both tiles
// staged via global_load_lds width=16 into chunk-swizzled LDS (0 conflicts).
// Grid 4096 1-D: k_tile=(b>>3)&7, i_tile=(b&7)|((b>>6)<<3) -> the 8 k-tiles
// of an i-tile share an XCD (b%8 round-robin); enc fetched from HBM ~once.
// ---------------------------------------------------------------------------
__device__ inline void stage_tile(const ushort_t* __restrict__ gbase,
                                  ushort_t* lds, int tid, size_t row0_off) {
#pragma unroll
    for (int j = 0; j < 2; j++) {
        int c_lin = j * 256 + tid;
        int r  = c_lin >> 2;
        int cp = c_lin & 3;
        int q  = cp ^ ((r >> 1) & 3);
        const ushort_t* g = gbase + row0_off + (size_t)r * H_ + q * 8;
        ushort_t* l = lds + (size_t)(j * 256 + (tid & ~63)) * 8;  // wave-uniform
        __builtin_amdgcn_global_load_lds((const __attribute__((address_space(1))) void*)g,
                                         (__attribute__((address_space(3))) void*)l,
                                         16, 0, 0);
    }
}

__global__ __launch_bounds__(256) void score_mfma_kernel(const ushort_t* __restrict__ enc_bf,
                                                         const ushort_t* __restrict__ ws_bf,
                                                         const float* __restrict__ dh,
                                                         const float* __restrict__ v,
                                                         float* __restrict__ score) {
    __shared__ ushort_t As[128 * 32];   // 8 KB
    __shared__ ushort_t Bs[128 * 32];   // 8 KB

    const int b  = blockIdx.x;
    const int i0 = ((b & 7) | ((b >> 6) << 3)) * 128;   // i-tile base
    const int k0 = ((b >> 3) & 7) * 128;                // k-tile base
    const int tid  = threadIdx.x;
    const int lane = tid & 63;
    const int wv   = tid >> 6;
    const int wr   = (wv >> 1) * 64;    // wave row base in tile
    const int wc   = (wv & 1) * 64;     // wave col base in tile
    const int m    = lane & 15;
    const int q    = lane >> 4;
    const int qs   = q ^ ((m >> 1) & 3);  // swizzled chunk col for reads

    f32x4 acc[4][4];
#pragma unroll
    for (int a = 0; a < 4; a++)
#pragma unroll
        for (int c = 0; c < 4; c++)
            acc[a][c] = (f32x4){0.f, 0.f, 0.f, 0.f};

    for (int h0 = 0; h0 < H_; h0 += 32) {
        __syncthreads();
        stage_tile(enc_bf, As, tid, (size_t)i0 * H_ + h0);
        stage_tile(ws_bf,  Bs, tid, (size_t)k0 * H_ + h0);
        __syncthreads();

        bf16x8 af[4], bfr[4];
#pragma unroll
        for (int ti = 0; ti < 4; ti++) {
            int r = wr + ti * 16 + m;
            af[ti] = *(const bf16x8*)(As + (size_t)(r * 4 + qs) * 8);
        }
#pragma unroll
        for (int tj = 0; tj < 4; tj++) {
            int r = wc + tj * 16 + m;
            bfr[tj] = *(const bf16x8*)(Bs + (size_t)(r * 4 + qs) * 8);
        }
#pragma unroll
        for (int ti = 0; ti < 4; ti++)
#pragma unroll
            for (int tj = 0; tj < 4; tj++)
                acc[ti][tj] = __builtin_amdgcn_mfma_f32_16x16x32_bf16(
                    af[ti], bfr[tj], acc[ti][tj], 0, 0, 0);
    }

    // Epilogue: x = dh + C; s_row += v[k] * tanh(x); wave-reduce over 64 k,
    // one atomicAdd per row per wave (into d_ws score buffer — normal memory).
    const int nb = i0 >> 10;            // batch index (tile never crosses n)
    float vv[4], dhv[4];
#pragma unroll
    for (int tj = 0; tj < 4; tj++) {
        int k = k0 + wc + tj * 16 + m;  // C/D col = lane&15
        vv[tj]  = v[k];
        dhv[tj] = dh[nb * H_ + k];
    }
#pragma unroll
    for (int ti = 0; ti < 4; ti++) {
#pragma unroll
        for (int reg = 0; reg < 4; reg++) {
            float s = 0.f;
#pragma unroll
            for (int tj = 0; tj < 4; tj++) {
                float x  = dhv[tj] + acc[ti][tj][reg];
                float e2 = __expf(2.f * x);
                s += vv[tj] * (1.f - 2.f / (e2 + 1.f));   // tanh, saturates +/-1
            }
            s += __shfl_xor(s, 1);
            s += __shfl_xor(s, 2);
            s += __shfl_xor(s, 4);
            s += __shfl_xor(s, 8);
            if (m == 0) {
                int i_local = wr + ti * 16 + q * 4 + reg;   // C/D row = quad*4+reg
                atomicAdd(&score[i0 + i_local], s);
            }
        }
    }
}

// ---------------------------------------------------------------------------
// K3: masked softmax over L per batch row; plain stores to d_out[65536..]
// ---------------------------------------------------------------------------
__global__ __launch_bounds__(256) void softmax_kernel(const float* __restrict__ score,
                                                      const int* __restrict__ mask,
                                                      float* __restrict__ attn) {
    const int n = blockIdx.x;
    const int t = threadIdx.x;
    __shared__ float redmax[4];
    __shared__ float redsum[4];

    float s[4];
    int   mk[4];
    float mymax = -INFINITY;
#pragma unroll
    for (int j = 0; j < 4; j++) {
        int l = t + j * 256;
        mk[j] = mask[n * L_ + l];
        s[j] = mk[j] ? -INFINITY : score[n * L_ + l];
        mymax = fmaxf(mymax, s[j]);
    }
#pragma unroll
    for (int off = 1; off < 64; off <<= 1)
        mymax = fmaxf(mymax, __shfl_xor(mymax, off));
    if ((t & 63) == 0) redmax[t >> 6] = mymax;
    __syncthreads();
    float gmax = fmaxf(fmaxf(redmax[0], redmax[1]), fmaxf(redmax[2], redmax[3]));

    float e[4];
    float mysum = 0.f;
#pragma unroll
    for (int j = 0; j < 4; j++) {
        e[j] = mk[j] ? 0.f : __expf(s[j] - gmax);
        mysum += e[j];
    }
#pragma unroll
    for (int off = 1; off < 64; off <<= 1)
        mysum += __shfl_xor(mysum, off);
    if ((t & 63) == 0) redsum[t >> 6] = mysum;
    __syncthreads();
    float gsum = redsum[0] + redsum[1] + redsum[2] + redsum[3];
    float inv = 1.f / gsum;
#pragma unroll
    for (int j = 0; j < 4; j++)
        attn[n * L_ + t + j * 256] = e[j] * inv;
}

// ---------------------------------------------------------------------------
// K4a: context partials — NO atomics to d_out.
// grid (64, 8): block (n, L-chunk of 128); 128 threads, 8 h each (bf16x8,
// 16B/lane). Partial sums -> d_ws cpart[lc][n][h] with plain float4 stores.
// ---------------------------------------------------------------------------
__global__ __launch_bounds__(128) void context_partial_kernel(const ushort_t* __restrict__ enc_bf,
                                                              const float* __restrict__ attn,
                                                              float* __restrict__ cpart) {
    const int n  = blockIdx.x;
    const int lc = blockIdx.y;
    const int l0 = lc * 128;
    const int t  = threadIdx.x;      // 0..127
    const int h0 = t * 8;

    __shared__ float w[128];
    w[t] = attn[n * L_ + l0 + t];
    __syncthreads();

    const ushort_t* base = enc_bf + (size_t)n * L_ * H_ + (size_t)l0 * H_ + h0;
    float acc[8] = {};
#pragma unroll 4
    for (int l = 0; l < 128; l++) {
        union { bf16x8 v; ushort_t u[8]; } e;
        e.v = *(const bf16x8*)(base + (size_t)l * H_);
        float wl = w[l];
#pragma unroll
        for (int j = 0; j < 8; j++)
            acc[j] += wl * __uint_as_float(((uint_t)e.u[j]) << 16);
    }
    float* dst = cpart + ((size_t)lc * N_ + n) * H_ + h0;
    *(float4*)(dst + 0) = (float4){acc[0], acc[1], acc[2], acc[3]};
    *(float4*)(dst + 4) = (float4){acc[4], acc[5], acc[6], acc[7]};
}

// ---------------------------------------------------------------------------
// K4b: reduce 8 partials -> ctx, plain stores to d_out
// ---------------------------------------------------------------------------
__global__ __launch_bounds__(256) void context_reduce_kernel(const float* __restrict__ cpart,
                                                             float* __restrict__ ctx) {
    int i = blockIdx.x * 256 + threadIdx.x;   // 0..65535  (= n*H + h)
    float s = 0.f;
#pragma unroll
    for (int lc = 0; lc < 8; lc++)
        s += cpart[(size_t)lc * N_ * H_ + i];
    ctx[i] = s;
}

// ---------------------------------------------------------------------------
extern "C" void kernel_launch(void* const* d_in, const int* in_sizes, int n_in,
                              void* d_out, int out_size, void* d_ws, size_t ws_size,
                              hipStream_t stream) {
    const float* ddec = (const float*)d_in[0];   // [64,1024] f32
    const float* enc  = (const float*)d_in[1];   // [64,1024,1024] f32
    const int*   mask = (const int*)d_in[2];     // [64,1024]
    const float* Wh   = (const float*)d_in[3];   // [1024,1024] f32
    const float* Ws   = (const float*)d_in[4];   // [1024,1024] f32
    const float* v    = (const float*)d_in[5];   // [1024] f32

    float* out_ctx  = (float*)d_out;             // [64,1024]
    float* out_attn = out_ctx + N_ * H_;         // [64,1024]

    // ws: enc_bf 128MB | ws_bf 2MB | dh 256KB | score 256KB | cpart 2MB
    ushort_t* enc_bf = (ushort_t*)d_ws;
    ushort_t* ws_bf  = enc_bf + (size_t)NL_ * H_;
    float*    dh     = (float*)(ws_bf + (size_t)H_ * H_);
    float*    score  = dh + N_ * H_;
    float*    cpart  = score + NL_;

    convert_bf16_kernel<<<4096, 256, 0, stream>>>(enc, enc_bf, (size_t)NL_ * H_ / 8);
    convert_bf16_kernel<<<512, 256, 0, stream>>>(Ws, ws_bf, (size_t)H_ * H_ / 8);

    hipMemsetAsync(score, 0, (size_t)NL_ * sizeof(float), stream);

    dh_kernel<<<NL_ / 256, 256, 0, stream>>>(ddec, Wh, dh);

    score_mfma_kernel<<<4096, 256, 0, stream>>>(enc_bf, ws_bf, dh, v, score);

    softmax_kernel<<<N_, 256, 0, stream>>>(score, mask, out_attn);

    dim3 g4(N_, 8);
    context_partial_kernel<<<g4, 128, 0, stream>>>(enc_bf, out_attn, cpart);
    context_reduce_kernel<<<NL_ / 1024 * 4, 256, 0, stream>>>(cpart, out_ctx);
}